// Round 3
// baseline (10182.452 us; speedup 1.0000x reference)
//
#include <hip/hip_runtime.h>
#include <math.h>

#define VV 32000
#define BB 32
#define TT 128
#define HH 512
#define G4 2048   // 4*HH
#define BTT 4096  // BB*TT

typedef unsigned short u16;
typedef __attribute__((ext_vector_type(8))) short short8;
typedef __attribute__((ext_vector_type(4))) float f32x4;

static __device__ __forceinline__ float sigm(float x) { return 1.0f / (1.0f + expf(-x)); }

// RNE split: v = hi + lo + eps, |eps| <= 2^-16 |v|
static __device__ __forceinline__ void bsplit(float v, u16& h, u16& l) {
    unsigned u = __float_as_uint(v);
    h = (u16)((u + 0x7FFFu + ((u >> 16) & 1u)) >> 16);
    float vh = __uint_as_float(((unsigned)h) << 16);
    unsigned u2 = __float_as_uint(v - vh);
    l = (u16)((u2 + 0x7FFFu + ((u2 >> 16) & 1u)) >> 16);
}

static __device__ __forceinline__ void gl_lds16(const void* g, void* l) {
    __builtin_amdgcn_global_load_lds(
        (const __attribute__((address_space(1))) void*)g,
        (__attribute__((address_space(3))) void*)l, 16, 0, 0);
}

// ---------- embedding gather + split ----------
__global__ void k_gather_split(const int* __restrict__ idx, const float* __restrict__ emb,
                               u16* __restrict__ hi, u16* __restrict__ lo) {
    int row = blockIdx.x;
    int e = idx[row];
    float4 v = ((const float4*)(emb + (size_t)e * HH))[threadIdx.x];
    ushort4 h4, l4;
    bsplit(v.x, h4.x, l4.x); bsplit(v.y, h4.y, l4.y);
    bsplit(v.z, h4.z, l4.z); bsplit(v.w, h4.w, l4.w);
    size_t o = (size_t)row * HH + threadIdx.x * 4;
    *(ushort4*)(hi + o) = h4;
    *(ushort4*)(lo + o) = l4;
}

// ---------- elementwise split, float4-vectorized ----------
__global__ void k_split4(const float* __restrict__ x, u16* __restrict__ hi,
                         u16* __restrict__ lo, int n4) {
    int i = blockIdx.x * 256 + threadIdx.x;
    if (i >= n4) return;
    float4 v = ((const float4*)x)[i];
    ushort4 h4, l4;
    bsplit(v.x, h4.x, l4.x); bsplit(v.y, h4.y, l4.y);
    bsplit(v.z, h4.z, l4.z); bsplit(v.w, h4.w, l4.w);
    *(ushort4*)(hi + (size_t)i * 4) = h4;
    *(ushort4*)(lo + (size_t)i * 4) = l4;
}

__global__ void k_zero(float* __restrict__ p, int n) {
    int i = blockIdx.x * blockDim.x + threadIdx.x;
    if (i < n) p[i] = 0.0f;
}

// ---------- fp32 transpose: dst[gc][k] = src[k][gc], k<K, gc<G4 ----------
__global__ void k_transposeN(const float* __restrict__ src, float* __restrict__ dst, int K) {
    int gc = blockIdx.x;
    float* d = dst + (size_t)gc * K;
    for (int k = threadIdx.x; k < K; k += blockDim.x)
        d[k] = src[(size_t)k * G4 + gc];
}

// ---------- transpose + split: src fp32 [K][N] -> dhi/dlo bf16 [N][K] ----------
__global__ __launch_bounds__(256) void k_tsplit(const float* __restrict__ src,
                                                u16* __restrict__ dhi, u16* __restrict__ dlo,
                                                int K, int N) {
    __shared__ float t[32][33];
    int kb = blockIdx.y << 5, nb = blockIdx.x << 5;
    int r = threadIdx.x >> 5, c = threadIdx.x & 31;
    #pragma unroll
    for (int it = 0; it < 4; ++it)
        t[it * 8 + r][c] = src[(size_t)(kb + it * 8 + r) * N + nb + c];
    __syncthreads();
    #pragma unroll
    for (int it = 0; it < 4; ++it) {
        int n = nb + it * 8 + r, k = kb + c;
        u16 h, l;
        bsplit(t[c][it * 8 + r], h, l);
        dhi[(size_t)n * K + k] = h;
        dlo[(size_t)n * K + k] = l;
    }
}

// ---------- bf16x3 split MFMA GEMM (m97-structure port): C = (Ah+Al)@(Bh+Bl)^T + bias ----------
__global__ __launch_bounds__(256) void k_mgemm(const u16* __restrict__ Ah, const u16* __restrict__ Al,
                                               const u16* __restrict__ Bh, const u16* __restrict__ Bl,
                                               const float* __restrict__ bias, float* __restrict__ C,
                                               int N, int K) {
    __shared__ u16 lds[4][4096];  // As_hi, As_lo, Bs_hi, Bs_lo : 8KB each
    const int tid = threadIdx.x;
    const int lane = tid & 63, wid = tid >> 6;
    const int wm = wid >> 1, wn = wid & 1;
    const int lm = lane & 15, kg = lane >> 4;
    const size_t mbase = (size_t)blockIdx.y * 128, nbase = (size_t)blockIdx.x * 128;

    f32x4 acc[4][4] = {};

    const int q = wid * 128 + lane;  // slot id base
    for (int k0 = 0; k0 < K; k0 += 32) {
        __syncthreads();
        #pragma unroll
        for (int i = 0; i < 2; ++i) {
            int qq = q + i * 64;
            int kgs = qq >> 7, ms = qq & 127;
            size_t ga = (mbase + ms) * K + k0 + kgs * 8;
            size_t gb = (nbase + ms) * K + k0 + kgs * 8;
            int lb_ = (wid * 2 + i) * 512;
            gl_lds16(Ah + ga, &lds[0][lb_]);
            gl_lds16(Al + ga, &lds[1][lb_]);
            gl_lds16(Bh + gb, &lds[2][lb_]);
            gl_lds16(Bl + gb, &lds[3][lb_]);
        }
        __syncthreads();

        short8 ah[4], al[4], bh[4], bl[4];
        const int abase = (kg * 128 + wm * 64 + lm) * 8;
        const int bbase = (kg * 128 + wn * 64 + lm) * 8;
        #pragma unroll
        for (int f = 0; f < 4; ++f) {
            ah[f] = *(const short8*)&lds[0][abase + f * 128];
            al[f] = *(const short8*)&lds[1][abase + f * 128];
            bh[f] = *(const short8*)&lds[2][bbase + f * 128];
            bl[f] = *(const short8*)&lds[3][bbase + f * 128];
        }
        #pragma unroll
        for (int fm = 0; fm < 4; ++fm)
            #pragma unroll
            for (int fn = 0; fn < 4; ++fn) {
                acc[fm][fn] = __builtin_amdgcn_mfma_f32_16x16x32_bf16(ah[fm], bh[fn], acc[fm][fn], 0, 0, 0);
                acc[fm][fn] = __builtin_amdgcn_mfma_f32_16x16x32_bf16(ah[fm], bl[fn], acc[fm][fn], 0, 0, 0);
                acc[fm][fn] = __builtin_amdgcn_mfma_f32_16x16x32_bf16(al[fm], bh[fn], acc[fm][fn], 0, 0, 0);
            }
    }

    float bv[4];
    #pragma unroll
    for (int fn = 0; fn < 4; ++fn) bv[fn] = bias[nbase + wn * 64 + fn * 16 + lm];
    #pragma unroll
    for (int fm = 0; fm < 4; ++fm) {
        size_t row0 = mbase + wm * 64 + fm * 16 + kg * 4;
        #pragma unroll
        for (int fn = 0; fn < 4; ++fn) {
            size_t col = nbase + wn * 64 + fn * 16 + lm;
            #pragma unroll
            for (int r = 0; r < 4; ++r)
                C[(row0 + r) * N + col] = acc[fm][fn][r] + bv[fn];
        }
    }
}

// ---------- pipelined 2-layer LSTM step ----------
// Launch s: L1 computes step t=s (if s<TT) in WGs [0,128); L2 computes step tt=s-1
// (if s>=1) in WGs [128,384). Kernel boundary = the only cross-layer sync.
// State (fp32, in ws): h1 ping-pong [2][32][512], c1 [32][512], h2 pp, c2.
__global__ __launch_bounds__(256) void k_stepP(const float* __restrict__ wt1,   // [2048][512]
                                               const float* __restrict__ wt2,   // [2048][1024]
                                               const float* __restrict__ xg1,   // [BTT][2048]
                                               const float* __restrict__ lb2,   // [2048]
                                               float* __restrict__ st,          // states base
                                               float* __restrict__ hall1,       // [BTT][512]
                                               float* __restrict__ hall2,       // [BTT][512]
                                               int s) {
    __shared__ float gs[512];
    float* h1buf[2] = {st, st + 16384};
    float* c1 = st + 2 * 16384;
    float* h2buf[2] = {st + 3 * 16384, st + 4 * 16384};
    float* c2 = st + 5 * 16384;
    const int tid = threadIdx.x;

    if (blockIdx.x < 128) {
        // ---- layer 1, step t = s ----
        int t = s;
        if (t >= TT) return;
        const int cg = blockIdx.x >> 1;       // 64 channel-groups of 8
        const int bg = blockIdx.x & 1;        // 2 batch-groups of 16
        const float* hp = h1buf[t & 1];
        float* hn = h1buf[(t & 1) ^ 1];
        const int b = tid >> 4, g = (tid >> 2) & 3, ch2 = tid & 3;
        const int batch = bg * 16 + b;
        const int gc0 = g * HH + cg * 8 + ch2;      // and gc0+4
        const float4* w0 = (const float4*)(wt1 + (size_t)gc0 * HH);
        const float4* w1 = (const float4*)(wt1 + (size_t)(gc0 + 4) * HH);
        const float4* hr = (const float4*)(hp + batch * HH);
        float a0 = 0.f, a1 = 0.f;
        #pragma unroll 4
        for (int i = 0; i < HH / 4; ++i) {
            float4 h4 = hr[i], x0 = w0[i], x1 = w1[i];
            a0 += x0.x * h4.x + x0.y * h4.y + x0.z * h4.z + x0.w * h4.w;
            a1 += x1.x * h4.x + x1.y * h4.y + x1.z * h4.z + x1.w * h4.w;
        }
        size_t xrow = ((size_t)batch * TT + t) * G4;
        gs[(b * 4 + g) * 8 + ch2]     = a0 + xg1[xrow + gc0];
        gs[(b * 4 + g) * 8 + ch2 + 4] = a1 + xg1[xrow + gc0 + 4];
        __syncthreads();
        if (tid < 128) {
            int bb = tid >> 3, cc = tid & 7;
            int batch2 = bg * 16 + bb, chan = cg * 8 + cc;
            float gi = gs[(bb * 4 + 0) * 8 + cc], gj = gs[(bb * 4 + 1) * 8 + cc];
            float gf = gs[(bb * 4 + 2) * 8 + cc], go = gs[(bb * 4 + 3) * 8 + cc];
            size_t ci = (size_t)batch2 * HH + chan;
            float nc = c1[ci] * sigm(gf) + sigm(gi) * tanhf(gj);
            float nh = tanhf(nc) * sigm(go);
            c1[ci] = nc;
            hn[ci] = nh;
            hall1[((size_t)batch2 * TT + t) * HH + chan] = nh;
        }
    } else {
        // ---- layer 2, step tt = s-1 ----
        int tt = s - 1;
        if (tt < 0) return;
        const int idx = blockIdx.x - 128;
        const int cg = idx >> 2;              // 64 channel-groups of 8
        const int bg = idx & 3;               // 4 batch-groups of 8
        const float* hp = h2buf[tt & 1];
        float* hn = h2buf[(tt & 1) ^ 1];
        const int b = tid >> 5, g = (tid >> 3) & 3, ch = tid & 7;
        const int batch = bg * 8 + b;
        const int gc = g * HH + cg * 8 + ch;
        const float4* wx = (const float4*)(wt2 + (size_t)gc * 1024);        // x-half (h1)
        const float4* wh = wx + HH / 4;                                      // h-half (h2)
        const float4* xr = (const float4*)(hall1 + ((size_t)batch * TT + tt) * HH);
        const float4* hr = (const float4*)(hp + batch * HH);
        float a = 0.f;
        #pragma unroll 4
        for (int i = 0; i < HH / 4; ++i) {
            float4 x4 = xr[i], w4 = wx[i];
            a += w4.x * x4.x + w4.y * x4.y + w4.z * x4.z + w4.w * x4.w;
        }
        #pragma unroll 4
        for (int i = 0; i < HH / 4; ++i) {
            float4 h4 = hr[i], w4 = wh[i];
            a += w4.x * h4.x + w4.y * h4.y + w4.z * h4.z + w4.w * h4.w;
        }
        gs[(b * 4 + g) * 8 + ch] = a + lb2[gc];
        __syncthreads();
        if (tid < 64) {
            int bb = tid >> 3, cc = tid & 7;
            int batch2 = bg * 8 + bb, chan = cg * 8 + cc;
            float gi = gs[(bb * 4 + 0) * 8 + cc], gj = gs[(bb * 4 + 1) * 8 + cc];
            float gf = gs[(bb * 4 + 2) * 8 + cc], go = gs[(bb * 4 + 3) * 8 + cc];
            size_t ci = (size_t)batch2 * HH + chan;
            float nc = c2[ci] * sigm(gf) + sigm(gi) * tanhf(gj);
            float nh = tanhf(nc) * sigm(go);
            c2[ci] = nc;
            hn[ci] = nh;
            hall2[((size_t)batch2 * TT + tt) * HH + chan] = nh;
        }
    }
}

// ---------- per-row CE loss: online logsumexp over V ----------
__global__ __launch_bounds__(256) void k_loss(const float* __restrict__ logits,
                                              const int* __restrict__ tgt,
                                              float* __restrict__ rowloss) {
    int row = blockIdx.x;
    const float* lr = logits + (size_t)row * VV;
    float m = -INFINITY, s = 0.f;
    for (int c = threadIdx.x; c < VV; c += 256) {
        float x = lr[c];
        if (x > m) { s = s * __expf(m - x) + 1.f; m = x; }
        else       { s += __expf(x - m); }
    }
    #pragma unroll
    for (int off = 32; off > 0; off >>= 1) {
        float mo = __shfl_down(m, off);
        float so = __shfl_down(s, off);
        if (mo > m) { s = s * __expf(m - mo) + so; m = mo; }
        else        { s += so * __expf(mo - m); }
    }
    __shared__ float sm[4], ss[4];
    int wid = threadIdx.x >> 6;
    if ((threadIdx.x & 63) == 0) { sm[wid] = m; ss[wid] = s; }
    __syncthreads();
    if (threadIdx.x == 0) {
        m = sm[0]; s = ss[0];
        for (int w = 1; w < 4; ++w) {
            float mo = sm[w], so = ss[w];
            if (mo > m) { s = s * __expf(m - mo) + so; m = mo; }
            else        { s += so * __expf(mo - m); }
        }
        float tl = lr[tgt[row]];
        rowloss[row] = -(tl - m - logf(s));
    }
}

__global__ void k_meanloss(const float* __restrict__ rowloss, float* __restrict__ out) {
    float s = 0.f;
    for (int i = threadIdx.x; i < BTT; i += 256) s += rowloss[i];
    #pragma unroll
    for (int off = 32; off > 0; off >>= 1) s += __shfl_down(s, off);
    __shared__ float wsum[4];
    int wid = threadIdx.x >> 6;
    if ((threadIdx.x & 63) == 0) wsum[wid] = s;
    __syncthreads();
    if (threadIdx.x == 0) out[0] = (wsum[0] + wsum[1] + wsum[2] + wsum[3]) * (1.0f / BTT);
}

extern "C" void kernel_launch(void* const* d_in, const int* in_sizes, int n_in,
                              void* d_out, int out_size, void* d_ws, size_t ws_size,
                              hipStream_t stream) {
    const int*   ids = (const int*)d_in[0];
    const int*   tgt = (const int*)d_in[1];
    const float* emb = (const float*)d_in[2];
    const float* lw  = (const float*)d_in[3];
    const float* lb  = (const float*)d_in[4];
    const float* sw  = (const float*)d_in[5];
    const float* sb  = (const float*)d_in[6];
    float* logits = (float*)d_out;
    float* cost   = logits + (size_t)BTT * VV;

    // ---- ws layout (floats first, then u16) ----
    float* hall1 = (float*)d_ws;            // 4096*512  (8MB)
    float* hall2 = hall1 + 2097152;         // 4096*512  (8MB)
    float* xgbuf = hall2 + 2097152;         // 4096*2048 (32MB)
    float* wt1   = xgbuf + 8388608;         // 2048*512  (4MB)
    float* wt2   = wt1 + 1048576;           // 2048*1024 (8MB)
    float* stt   = wt2 + 2097152;           // 6*16384 states
    float* rloss = stt + 98304;             // 4096
    u16* xa_hi  = (u16*)(rloss + 4096);     // [BTT][HH]   (4MB)
    u16* xa_lo  = xa_hi + (size_t)BTT * HH;
    u16* wxt_hi = xa_lo + (size_t)BTT * HH; // layer-0 Wx^T [2048][512] (2MB)
    u16* wxt_lo = wxt_hi + (size_t)G4 * HH;
    u16* swt_hi = wxt_lo + (size_t)G4 * HH; // [32000][512] (32.8MB)
    u16* swt_lo = swt_hi + (size_t)VV * HH;

    // ---- weight preprocessing ----
    k_transposeN<<<G4, 128, 0, stream>>>(lw + (size_t)HH * G4, wt1, HH);        // L1 h-half
    k_transposeN<<<G4, 128, 0, stream>>>(lw + (size_t)2 * HH * G4, wt2, 2 * HH); // L2 full
    {
        dim3 gt(G4 / 32, HH / 32);
        k_tsplit<<<gt, 256, 0, stream>>>(lw, wxt_hi, wxt_lo, HH, G4);           // L1 x-half
    }
    {
        dim3 gt(VV / 32, HH / 32);
        k_tsplit<<<gt, 256, 0, stream>>>(sw, swt_hi, swt_lo, HH, VV);
    }
    k_gather_split<<<BTT, 128, 0, stream>>>(ids, emb, xa_hi, xa_lo);
    k_zero<<<(98304 + 255) / 256, 256, 0, stream>>>(stt, 98304);

    // ---- layer-1 input gates: xg = x_emb @ W1x + b1 ----
    dim3 gg(G4 / 128, BTT / 128);
    k_mgemm<<<gg, 256, 0, stream>>>(xa_hi, xa_lo, wxt_hi, wxt_lo, lb, xgbuf, G4, HH);

    // ---- pipelined recurrence: 129 launches ----
    for (int s = 0; s <= TT; ++s)
        k_stepP<<<384, 256, 0, stream>>>(wt1, wt2, xgbuf, lb + G4, stt, hall1, hall2, s);

    // ---- projection ----
    k_split4<<<(BTT * HH / 4 + 255) / 256, 256, 0, stream>>>(hall2, xa_hi, xa_lo, BTT * HH / 4);
    dim3 gp(VV / 128, BTT / 128);
    k_mgemm<<<gp, 256, 0, stream>>>(xa_hi, xa_lo, swt_hi, swt_lo, sb, logits, VV, HH);
    k_loss<<<BTT, 256, 0, stream>>>(logits, tgt, rloss);
    k_meanloss<<<1, 256, 0, stream>>>(rloss, cost);
}